// Round 2
// baseline (915.471 us; speedup 1.0000x reference)
//
#include <hip/hip_runtime.h>
#include <math.h>

typedef _Float16 half8 __attribute__((ext_vector_type(8)));
typedef _Float16 half4 __attribute__((ext_vector_type(4)));
typedef __fp16   fp16x2 __attribute__((ext_vector_type(2)));   // cvt_pkrtz return type
typedef float    f32x16 __attribute__((ext_vector_type(16)));

#define T_DIM 36
#define N_AT 40
#define K_REAL 161
#define MT2 6           // 6 M-tiles of 32 = 192 rows (161 real)
#define KS 11           // 11 MFMA K-steps of 16 = 176 >= 161 (col-160 folded in, no rank-1)
#define TKS 3           // DtY K-steps over t (36 -> 48)
#define B_DIM 2
#define F_DIM 20480
#define CB 32           // columns per block = one 32-col MFMA N-tile
#define NTHREADS 384    // 6 waves (one 32-row M-tile each); 2 blocks/CU -> 3 waves/SIMD
#define SETUP_T 512     // frag builder needs tid>>3 to span 64 lanes
#define MAXIT 100
#define YK 200          // padded k-stride in y LDS (f16): 400B row = shift-4 banks
#define YST 72          // staging t-stride (f16)

// ws layout (bytes): scalars | A-hat frags (32x32x16 layout) | Dthat frags
#define WS_AFRAG_OFF 64
#define AFRAG_BYTES (MT2 * KS * 2 * 1024)     // 66 frags * 2 terms * 1KB = 135168
#define WS_DFRAG_OFF (WS_AFRAG_OFF + AFRAG_BYTES)
#define DFRAG_BYTES (MT2 * TKS * 2 * 1024)    // 36864

#define MFMA32(a, b, c) __builtin_amdgcn_mfma_f32_32x32x16_f16((a), (b), (c), 0, 0, 0)

__global__ void setup_kernel(const float* __restrict__ Drr,
                             const float* __restrict__ Dtheta,
                             float* __restrict__ ws) {
    __shared__ float Dl[K_REAL][T_DIM];
    __shared__ float red[SETUP_T];
    __shared__ float s_linv;
    int tid = threadIdx.x;

    if (tid < K_REAL) {
        float col[T_DIM];
        if (tid == 0) {
            for (int i = 0; i < T_DIM; ++i) col[i] = 1.0f;
        } else {
            int q = (tid - 1) / N_AT, n = (tid - 1) % N_AT;
            float r = Drr[n], th = Dtheta[n];
            float ri = 1.0f;
            for (int i = 0; i < T_DIM; ++i) {
                float c = cosf((float)i * th), s = sinf((float)i * th);
                float sign = (i & 1) ? -1.0f : 1.0f;
                float v;
                if (q == 0)      v = ri * c;
                else if (q == 1) v = sign * ri * c;
                else if (q == 2) v = ri * s;
                else             v = sign * ri * s;
                col[i] = v;
                ri *= r;
            }
        }
        float ss = 0.0f;
        for (int i = 0; i < T_DIM; ++i) ss += col[i] * col[i];
        float G = sqrtf(ss);
        float Ginv = (G == 0.0f) ? (1.0f / sqrtf((float)T_DIM)) : (1.0f / G);
        for (int i = 0; i < T_DIM; ++i) Dl[tid][i] = col[i] * Ginv;
    }
    __syncthreads();

    float local = 0.0f;
    for (int p = tid; p < K_REAL * K_REAL; p += SETUP_T) {
        int a = p / K_REAL, b = p % K_REAL;
        float dot = 0.0f;
        for (int i = 0; i < T_DIM; ++i) dot += Dl[a][i] * Dl[b][i];
        local += dot * dot;
    }
    red[tid] = local;
    __syncthreads();
    if (tid == 0) {
        float tot = 0.0f;
        for (int i = 0; i < SETUP_T; ++i) tot += red[i];
        float linv = 1.0f / sqrtf(tot);
        s_linv = linv;
        ws[0] = linv;
        ws[1] = 0.1f * linv;
    }
    __syncthreads();
    float linv = s_linv;

    // ---- A-hat fragments for 32x32x16 MFMA: m = Mt*32 + (lane&31),
    //      k = ks*16 + (lane>>5)*8 + e.  hi/lo f16 split per element. ----
    _Float16* wsA = (_Float16*)((char*)ws + WS_AFRAG_OFF);
    int lane = tid >> 3, e = tid & 7;
    int lm = lane & 31, lhi = lane >> 5;
    for (int p = 0; p < MT2 * KS; ++p) {
        int Mt = p / KS, ks = p % KS;
        int m = Mt * 32 + lm;
        int k = ks * 16 + lhi * 8 + e;
        float v = 0.0f;
        if (m < K_REAL && k < K_REAL) {
            float dot = 0.0f;
            for (int t = 0; t < T_DIM; ++t) dot += Dl[m][t] * Dl[k][t];
            v = ((m == k) ? 1.0f : 0.0f) - linv * dot;
        }
        _Float16 h = (_Float16)v;
        _Float16 l = (_Float16)(v - (float)h);
        int base = (p * 2) * 512 + lane * 8 + e;
        wsA[base]       = h;
        wsA[base + 512] = l;
    }

    // ---- Dthat fragments: kr = Mt*32 + (lane&31), t = ks2*16 + (lane>>5)*8 + e ----
    _Float16* wsD = (_Float16*)((char*)ws + WS_DFRAG_OFF);
    for (int p = 0; p < MT2 * TKS; ++p) {
        int Mt = p / TKS, ks2 = p % TKS;
        int kr = Mt * 32 + lm;
        int t  = ks2 * 16 + lhi * 8 + e;
        float v = (kr < K_REAL && t < T_DIM) ? linv * Dl[kr][t] : 0.0f;
        _Float16 h = (_Float16)v;
        _Float16 l = (_Float16)(v - (float)h);
        int base = (p * 2) * 512 + lane * 8 + e;
        wsD[base]       = h;
        wsD[base + 512] = l;
    }
}

// epilogue: softshrink + momentum + f16 hi/lo y-write (swizzled chunks)
__device__ __forceinline__ void epi_write(const f32x16& acc, float (&xold)[16],
                                          _Float16* rowH, _Float16* rowL,
                                          float lam, float tt,
                                          int wv, int sw, int hi) {
    #pragma unroll
    for (int g = 0; g < 4; ++g) {
        float yn[4];
        #pragma unroll
        for (int i = 0; i < 4; ++i) {
            int r = g * 4 + i;
            float v  = acc[r];
            float s  = fmaxf(fabsf(v) - lam, 0.0f);
            float xn = copysignf(s, v);
            yn[i] = xn + tt * (xn - xold[r]);   // == (1+tt)xn - tt*xold
            xold[r] = xn;
        }
        fp16x2 h01 = __builtin_amdgcn_cvt_pkrtz(yn[0], yn[1]);
        fp16x2 h23 = __builtin_amdgcn_cvt_pkrtz(yn[2], yn[3]);
        float l0 = yn[0] - (float)h01[0];
        float l1 = yn[1] - (float)h01[1];
        float l2 = yn[2] - (float)h23[0];
        float l3 = yn[3] - (float)h23[1];
        fp16x2 l01 = __builtin_amdgcn_cvt_pkrtz(l0, l1);
        fp16x2 l23 = __builtin_amdgcn_cvt_pkrtz(l2, l3);
        half4 hv, lv;
        hv[0] = (_Float16)h01[0]; hv[1] = (_Float16)h01[1];
        hv[2] = (_Float16)h23[0]; hv[3] = (_Float16)h23[1];
        lv[0] = (_Float16)l01[0]; lv[1] = (_Float16)l01[1];
        lv[2] = (_Float16)l23[0]; lv[3] = (_Float16)l23[1];
        // k0 = wv*32 + 8g + 4hi -> chunk j = wv*4 + g, byte-in-chunk = 8*hi
        int boff = (((wv * 4 + g) ^ sw) << 4) + (hi << 3);
        *(half4*)((char*)rowH + boff) = hv;
        *(half4*)((char*)rowL + boff) = lv;
    }
}

__global__ void __launch_bounds__(NTHREADS, 3)
fista_mfma(const float* __restrict__ Y, const float* __restrict__ ws,
           float* __restrict__ out) {
    // double-buffered y (hi/lo): 2 x 2 x 32 x 200 f16 = 51.2 KB -> 2 blocks/CU
    __shared__ __align__(16) _Float16 Yb_lds[2][2][CB][YK];

    const float lam = ((const float*)ws)[1];
    const half8* Afp = (const half8*)((const char*)ws + WS_AFRAG_OFF);
    const half8* Dfp = (const half8*)((const char*)ws + WS_DFRAG_OFF);

    const int tid  = threadIdx.x;
    const int lane = tid & 63;
    const int wv   = __builtin_amdgcn_readfirstlane(tid >> 6); // 0..5 = M-tile
    const int c    = lane & 31;      // F-column within block (B operand n, C/D col)
    const int hi   = lane >> 5;      // k-group for A/B operands
    const int sw   = (c >> 3) & 3;   // chunk-XOR swizzle key (de-alias shift-4 rows)

    const int blk = blockIdx.x;
    const int b   = blk / (F_DIM / CB);
    const int f0  = (blk % (F_DIM / CB)) * CB;

    // ---- stage Y (f16 hi/lo, [c][t], stride YST) into buffer 0 space ----
    _Float16* sh = &Yb_lds[0][0][0][0];
    _Float16* sl = &Yb_lds[0][1][0][0];
    const float* Yb = Y + (size_t)b * T_DIM * F_DIM + f0;
    for (int idx = tid; idx < 48 * CB; idx += NTHREADS) {
        int t = idx >> 5, cc = idx & 31;
        float v = (t < T_DIM) ? Yb[(size_t)t * F_DIM + cc] : 0.0f;
        _Float16 h = (_Float16)v;
        _Float16 l = (_Float16)(v - (float)h);
        sh[cc * YST + t] = h;
        sl[cc * YST + t] = l;
    }
    __syncthreads();

    // ---- DtY via 32x32x16 MFMA (3-term hi/lo split) ----
    f32x16 dty;
    #pragma unroll
    for (int i = 0; i < 16; ++i) dty[i] = 0.0f;
    #pragma unroll
    for (int ks2 = 0; ks2 < TKS; ++ks2) {
        half8 yh = *(const half8*)&sh[c * YST + ks2 * 16 + hi * 8];
        half8 yl = *(const half8*)&sl[c * YST + ks2 * 16 + hi * 8];
        half8 dh = Dfp[((wv * TKS + ks2) * 2 + 0) * 64 + lane];
        half8 dl = Dfp[((wv * TKS + ks2) * 2 + 1) * 64 + lane];
        dty = MFMA32(dh, yh, dty);
        dty = MFMA32(dh, yl, dty);
        dty = MFMA32(dl, yh, dty);
    }
    __syncthreads();   // staged data consumed; epi(1) may overwrite buffer 0

    // ---- persistent A-hat fragments (88 regs; STATIC indexing only) ----
    half8 Af[KS][2];
    #pragma unroll
    for (int ks = 0; ks < KS; ++ks)
        #pragma unroll
        for (int term = 0; term < 2; ++term)
            Af[ks][term] = Afp[((wv * KS + ks) * 2 + term) * 64 + lane];

    float xold[16];
    #pragma unroll
    for (int r = 0; r < 16; ++r) xold[r] = 0.0f;

    // step 1 is free: y_0 = 0 -> acc_1 = dty
    f32x16 acc = dty;

    // t-sequence: t_0=1 -> t_1=(1+sqrt5)/2, tt_1 = 0
    float tm = 1.61803398875f;

    // epi(1): writes buffer 0 (covers all k rows across the 6 waves)
    epi_write(acc, xold, &Yb_lds[0][0][c][0], &Yb_lds[0][1][c][0],
              lam, 0.0f, wv, sw, hi);
    __syncthreads();

    for (int s = 2; s <= MAXIT; ++s) {
        float tn = 0.5f * (1.0f + sqrtf(1.0f + 4.0f * tm * tm));
        float tt = (tm - 1.0f) / tn;
        tm = tn;

        const int p = s & 1;            // sweep reads buf[p], epi writes buf[p^1]
        const _Float16* rH = &Yb_lds[p][0][c][0];
        const _Float16* rL = &Yb_lds[p][1][c][0];

        // ---- sweep: acc = A-hat * y  (11 K-steps, 3-term split) ----
        #pragma unroll
        for (int ks = 0; ks < KS; ++ks) {
            int boff = ((2 * ks + hi) ^ sw) << 4;
            half8 yh = *(const half8*)((const char*)rH + boff);
            half8 yl = *(const half8*)((const char*)rL + boff);
            f32x16 c0 = (ks == 0) ? dty : acc;
            c0  = MFMA32(Af[ks][0], yh, c0);
            c0  = MFMA32(Af[ks][0], yl, c0);
            acc = MFMA32(Af[ks][1], yh, c0);
        }

        // ---- epilogue into the other buffer; one barrier per iteration ----
        epi_write(acc, xold, &Yb_lds[p ^ 1][0][c][0], &Yb_lds[p ^ 1][1][c][0],
                  lam, tt, wv, sw, hi);
        __syncthreads();
    }

    // ---- output x (fp32): k = wv*32 + (r&3) + 8*(r>>2) + 4*hi, col = c ----
    float* ob = out + (size_t)b * K_REAL * F_DIM + f0 + c;
    #pragma unroll
    for (int g = 0; g < 4; ++g)
        #pragma unroll
        for (int i = 0; i < 4; ++i) {
            int k = wv * 32 + i + 8 * g + 4 * hi;
            if (k < K_REAL) ob[(size_t)k * F_DIM] = xold[g * 4 + i];
        }
}

extern "C" void kernel_launch(void* const* d_in, const int* in_sizes, int n_in,
                              void* d_out, int out_size, void* d_ws, size_t ws_size,
                              hipStream_t stream) {
    const float* x      = (const float*)d_in[0];
    const float* Drr    = (const float*)d_in[1];
    const float* Dtheta = (const float*)d_in[2];
    float* out = (float*)d_out;
    float* ws  = (float*)d_ws;

    hipLaunchKernelGGL(setup_kernel, dim3(1), dim3(SETUP_T), 0, stream,
                       Drr, Dtheta, ws);
    hipLaunchKernelGGL(fista_mfma, dim3((B_DIM * F_DIM) / CB), dim3(NTHREADS),
                       0, stream, x, ws, out);
}